// Round 12
// baseline (270.056 us; speedup 1.0000x reference)
//
#include <hip/hip_runtime.h>
#include <math.h>

#define NUM_EMB 1024
#define EMB_DIM 256
#define N_ROWS  65536
#define HW      1024
#define QUANT_OFF 1
#define IDX_OFF   (1 + 16777216)
#define LDA 264   // halfs per A-row: 528B stride, affine addressing only (swizzle cost ~30 regs, r10)
#define KSTR 132  // key-scratch row stride in dwords

typedef unsigned int uint;
typedef _Float16 f16x8 __attribute__((ext_vector_type(8)));
typedef float    f32x4 __attribute__((ext_vector_type(4)));

__device__ __forceinline__ uint umin2(uint a, uint b) { return a < b ? a : b; }
__device__ __forceinline__ uint umax2(uint a, uint b) { return a > b ? a : b; }

// median of 3 == 2nd-largest of 3; single VALU op on gfx9+
__device__ __forceinline__ uint umed3(uint a, uint b, uint c) {
  uint d;
  asm("v_med3_u32 %0, %1, %2, %3" : "=v"(d) : "v"(a), "v"(b), "v"(c));
  return d;
}

// ---- kernel 1: normalize codebook -> wn (f32), wh2 (f16, MFMA-B-swizzled), rinv (f64) ----
// wh2 halfs layout: [chunk(4)][ks(8)][q(4)][code-in-chunk(256)][e(8)], d = ks*32+q*8+e.
// Linear slab s = chunk*8+ks at byte offset s*16384 (8192 halfs).
__global__ __launch_bounds__(256)
void k_norm_w(const float* __restrict__ w, float* __restrict__ wn,
              _Float16* __restrict__ wh2, double* __restrict__ rinv) {
  const int k = blockIdx.x, t = threadIdx.x;
  const float v = w[(size_t)k * EMB_DIM + t];
  double s = (double)v * (double)v;
  for (int o = 32; o; o >>= 1) s += __shfl_down(s, o);
  __shared__ double ps[4];
  if ((t & 63) == 0) ps[t >> 6] = s;
  __syncthreads();
  const double tot = ps[0] + ps[1] + ps[2] + ps[3];
  const float nv = v / fmaxf((float)sqrt(tot), 1e-12f);
  wn[(size_t)k * EMB_DIM + t] = nv;
  const int chunk = k >> 8, cc = k & 255;
  const int ks = t >> 5, q = (t >> 3) & 3, e = t & 7;
  wh2[(size_t)chunk * 65536 + ks * 8192 + q * 2048 + cc * 8 + e] = (_Float16)nv;
  if (t == 0) rinv[k] = 1.0 / fmax(sqrt(tot), 1e-12);
}

// ---- fused kernel (r4 structure + depth-2 B pipeline + direct quant) ----
// 1024 blocks x 256 thr, 64 rows/block. xv[64] f32 held through GEMM (r4-proven,
// ~2 waves/SIMD under (256,2), no spill). B: depth-2 prefetch via 3 NAMED buffers,
// 32-step fully-static schedule (consume s%3, prefetch (s+2)%3) -- rule #20 safe.
// Reg ledger: xv 64 + bufs 48 + t1/t2 32 + addr ~20 = ~164 arch + 64 AGPR = 228 <= 256.
// Quant: direct stores (ph==wave, lane==row -> per-d dword store is 256B coalesced).
__global__ __launch_bounds__(256, 2)
void k_fused(const float* __restrict__ x, const _Float16* __restrict__ wh2,
             const float* __restrict__ w, const float* __restrict__ wn,
             const double* __restrict__ rinv, float* __restrict__ out) {
  __shared__ __align__(16) _Float16 As[64 * LDA];   // 33792 B; reused: keys / red
  __shared__ uint4 cand_s[64];
  __shared__ int   cw_s[64];
  const int t = threadIdx.x;
  const int blk = blockIdx.x;
  const int b = blk >> 4;
  const int hw0 = (blk & 15) * 64;

  const int lane = t & 63;
  const int q = lane >> 4;
  const int l15 = lane & 15;
  const int w4id = t >> 6;

  // per-lane B element offsets (halfs) within a ks-slab of wh2
  const int bvo0 = q * 2048 + (w4id * 64 +  0 + l15) * 8;
  const int bvo1 = q * 2048 + (w4id * 64 + 16 + l15) * 8;
  const int bvo2 = q * 2048 + (w4id * 64 + 32 + l15) * 8;
  const int bvo3 = q * 2048 + (w4id * 64 + 48 + l15) * 8;

#define LOADB(buf, s)                                       \
  { const _Float16* ksb_ = wh2 + (size_t)(s) * 8192;        \
    buf[0] = *(const f16x8*)&ksb_[bvo0];                    \
    buf[1] = *(const f16x8*)&ksb_[bvo1];                    \
    buf[2] = *(const f16x8*)&ksb_[bvo2];                    \
    buf[3] = *(const f16x8*)&ksb_[bvo3]; }

  // 3 named B buffers, depth-2: step s consumes s%3, prefetches s+2 into (s+2)%3
  // ((s+2)%3 was consumed at step s-1 -> free). All names static.
  f16x8 bA[4], bB[4], bC[4];
  LOADB(bA, 0);   // s=0
  LOADB(bB, 1);   // s=1   (both overlap A staging)

  // stage A: x[b, d, hw0+r] f32 -> As[r][d] f16; KEEP the f32 values in registers
  const int r_own = t & 63;       // row this thread owns (staging, recheck, quant)
  const int ph = t >> 6;          // d-range: ph*64 .. ph*64+63  (ph == wave id)
  float xv[64];
  {
    const float* xb = x + (size_t)b * (EMB_DIM * HW) + hw0 + r_own;
#pragma unroll
    for (int jp = 0; jp < 8; ++jp) {
      const int d0 = ph * 64 + jp * 8;
      f16x8 v;
#pragma unroll
      for (int e = 0; e < 8; ++e) {
        const float f = xb[(size_t)(d0 + e) * HW];
        xv[jp * 8 + e] = f;
        v[e] = (_Float16)f;
      }
      *(f16x8*)&As[r_own * LDA + d0] = v;
    }
  }
  __syncthreads();   // A tile staged

  uint t1[16], t2[16];
#pragma unroll
  for (int i = 0; i < 16; ++i) { t1[i] = 0u; t2[i] = 0u; }

  // one K-step: prefetch s+2 into PREB, ds_read 4 A-frags at ks=s&7, 16 MFMAs on CURB
#define MMSTEP(sv, CURB, PREB)                                                          \
  { if ((sv) + 2 < 32) { LOADB(PREB, (sv) + 2); }                                       \
    const f16x8 a0 = *(const f16x8*)&As[( 0 + l15) * LDA + ((sv) & 7) * 32 + q * 8];    \
    const f16x8 a1 = *(const f16x8*)&As[(16 + l15) * LDA + ((sv) & 7) * 32 + q * 8];    \
    const f16x8 a2 = *(const f16x8*)&As[(32 + l15) * LDA + ((sv) & 7) * 32 + q * 8];    \
    const f16x8 a3 = *(const f16x8*)&As[(48 + l15) * LDA + ((sv) & 7) * 32 + q * 8];    \
    __builtin_amdgcn_s_setprio(1);                                                      \
    _Pragma("unroll")                                                                   \
    for (int ct = 0; ct < 4; ++ct) {                                                    \
      acc[0][ct] = __builtin_amdgcn_mfma_f32_16x16x32_f16(a0, CURB[ct], acc[0][ct], 0, 0, 0); \
      acc[1][ct] = __builtin_amdgcn_mfma_f32_16x16x32_f16(a1, CURB[ct], acc[1][ct], 0, 0, 0); \
      acc[2][ct] = __builtin_amdgcn_mfma_f32_16x16x32_f16(a2, CURB[ct], acc[2][ct], 0, 0, 0); \
      acc[3][ct] = __builtin_amdgcn_mfma_f32_16x16x32_f16(a3, CURB[ct], acc[3][ct], 0, 0, 0); \
    }                                                                                   \
    __builtin_amdgcn_s_setprio(0); }

#define ACCINIT                                                                         \
  f32x4 acc[4][4];                                                                      \
  _Pragma("unroll")                                                                     \
  for (int rt = 0; rt < 4; ++rt)                                                        \
    _Pragma("unroll")                                                                   \
    for (int ct = 0; ct < 4; ++ct) acc[rt][ct] = (f32x4)0.f;

#define MERGE(c4v)                                                                      \
  _Pragma("unroll")                                                                     \
  for (int ct = 0; ct < 4; ++ct) {                                                      \
    const uint idxv = (uint)((c4v) * 256 + w4id * 64 + ct * 16 + l15);                  \
    _Pragma("unroll")                                                                   \
    for (int rt = 0; rt < 4; ++rt)                                                      \
      _Pragma("unroll")                                                                 \
      for (int r = 0; r < 4; ++r) {                                                     \
        const float v = fmaxf(acc[rt][ct][r], 0.0f);                                    \
        const uint key = (__float_as_uint(v) & 0xFFFFFC00u) | idxv;                     \
        const int slot = rt * 4 + r;                                                    \
        t2[slot] = umed3(key, t1[slot], t2[slot]);                                      \
        t1[slot] = umax2(key, t1[slot]);                                                \
      }                                                                                 \
  }

  { ACCINIT
    MMSTEP( 0, bA, bC) MMSTEP( 1, bB, bA) MMSTEP( 2, bC, bB) MMSTEP( 3, bA, bC)
    MMSTEP( 4, bB, bA) MMSTEP( 5, bC, bB) MMSTEP( 6, bA, bC) MMSTEP( 7, bB, bA)
    MERGE(0) }
  { ACCINIT
    MMSTEP( 8, bC, bB) MMSTEP( 9, bA, bC) MMSTEP(10, bB, bA) MMSTEP(11, bC, bB)
    MMSTEP(12, bA, bC) MMSTEP(13, bB, bA) MMSTEP(14, bC, bB) MMSTEP(15, bA, bC)
    MERGE(1) }
  { ACCINIT
    MMSTEP(16, bB, bA) MMSTEP(17, bC, bB) MMSTEP(18, bA, bC) MMSTEP(19, bB, bA)
    MMSTEP(20, bC, bB) MMSTEP(21, bA, bC) MMSTEP(22, bB, bA) MMSTEP(23, bC, bB)
    MERGE(2) }
  { ACCINIT
    MMSTEP(24, bA, bC) MMSTEP(25, bB, bA) MMSTEP(26, bC, bB) MMSTEP(27, bA, bC)
    MMSTEP(28, bB, bA) MMSTEP(29, bC, bB) MMSTEP(30, bA, bC) MMSTEP(31, bB, bA)
    MERGE(3) }
#undef MMSTEP
#undef ACCINIT
#undef MERGE
#undef LOADB

  // ---- block-level per-row top-4 (reuse A LDS as key scratch: 64 rows x KSTR dwords) ----
  __syncthreads();   // all waves done with As
  uint* keys = (uint*)As;
#pragma unroll
  for (int slot = 0; slot < 16; ++slot) {
    const int rt = slot >> 2, r = slot & 3;
    const int row = rt * 16 + q * 4 + r;
    const int col = w4id * 32 + l15 * 2;
    keys[row * KSTR + col] = t1[slot];
    keys[row * KSTR + col + 1] = t2[slot];
  }
  __syncthreads();
  {
    const int row = t >> 2, seg = t & 3;   // 4 threads per row, 32 keys each
    uint s1 = 0, s2 = 0;
#pragma unroll
    for (int i = 0; i < 8; ++i) {
      const int ii = (i + t) & 7;
      const uint4 k4 = *(const uint4*)&keys[row * KSTR + seg * 32 + ii * 4];
      const uint kk[4] = {k4.x, k4.y, k4.z, k4.w};
#pragma unroll
      for (int e = 0; e < 4; ++e) {
        s2 = umed3(kk[e], s1, s2);
        s1 = umax2(kk[e], s1);
      }
    }
    __syncthreads();
    keys[t * 2] = s1;
    keys[t * 2 + 1] = s2;
  }
  __syncthreads();
  if (t < 64) {
    uint c0 = 0, c1 = 0, c2 = 0, c3 = 0;
#pragma unroll
    for (int i = 0; i < 8; ++i) {
      const uint k = keys[t * 8 + i];
      const uint n0 = umin2(c0, k); c0 = umax2(c0, k);
      const uint n1 = umin2(c1, n0); c1 = umax2(c1, n0);
      const uint n2 = umin2(c2, n1); c2 = umax2(c2, n1);
      c3 = umax2(c3, n2);
    }
    uint4 o; o.x = c0; o.y = c1; o.z = c2; o.w = c3;
    cand_s[t] = o;
  }
  __syncthreads();

  // ---- fp64 recheck: each thread covers its own (row, 64-d slice) with xv in regs ----
  double* red = (double*)As;   // 256 threads x 5 doubles = 10240 B
  {
    const uint4 ck = cand_s[r_own];
    const uint cv[4] = {ck.x, ck.y, ck.z, ck.w};
    double sxx_p = 0.0;
#pragma unroll
    for (int i = 0; i < 64; ++i) sxx_p = fma((double)xv[i], (double)xv[i], sxx_p);
#pragma unroll
    for (int j = 0; j < 4; ++j) {
      const int c = (int)(cv[j] & 1023u);
      const float* wr = w + (size_t)c * EMB_DIM + ph * 64;
      double s = 0.0;
#pragma unroll
      for (int k = 0; k < 16; ++k) {
        const float4 wv = *(const float4*)&wr[k * 4];
        s = fma((double)xv[k * 4 + 0], (double)wv.x, s);
        s = fma((double)xv[k * 4 + 1], (double)wv.y, s);
        s = fma((double)xv[k * 4 + 2], (double)wv.z, s);
        s = fma((double)xv[k * 4 + 3], (double)wv.w, s);
      }
      red[t * 5 + j] = s;
    }
    red[t * 5 + 4] = sxx_p;
  }
  __syncthreads();

  // ---- per-row decision (wave 0), loss reduce, idx store ----
  if (t < 64) {
    const uint4 ck = cand_s[t];
    const uint cv[4] = {ck.x, ck.y, ck.z, ck.w};
    double sj[4] = {0.0, 0.0, 0.0, 0.0};
    double sxx = 0.0;
#pragma unroll
    for (int p = 0; p < 4; ++p) {
      const int base = (p * 64 + t) * 5;
      sj[0] += red[base + 0];
      sj[1] += red[base + 1];
      sj[2] += red[base + 2];
      sj[3] += red[base + 3];
      sxx   += red[base + 4];
    }
    double qbest = -1e300; int cw = 1 << 30;
#pragma unroll
    for (int j = 0; j < 4; ++j) {
      const int c = (int)(cv[j] & 1023u);
      const double qj = sj[j] * rinv[c];
      if (qj > qbest || (qj == qbest && c < cw)) { qbest = qj; cw = c; }
    }
    const double dmin = 2.0 - 2.0 * qbest / fmax(sqrt(sxx), 1e-12);
    out[IDX_OFF + blk * 64 + t] = (float)cw;
    cw_s[t] = cw;
    double v = dmin;
    v += __shfl_down(v, 32);
    v += __shfl_down(v, 16);
    v += __shfl_down(v, 8);
    v += __shfl_down(v, 4);
    v += __shfl_down(v, 2);
    v += __shfl_down(v, 1);
    if (t == 0)
      atomicAdd(out, (float)(1.25 * v / 16777216.0));
  }
  __syncthreads();

  // ---- quant: direct coalesced stores (per-d dword store = 64 lanes x 256B contiguous) ----
  {
    const int cw = cw_s[r_own];
    const float* wr = wn + (size_t)cw * EMB_DIM + ph * 64;
    float* qo = out + QUANT_OFF + (size_t)b * (EMB_DIM * HW) + hw0 + r_own;
#pragma unroll
    for (int k = 0; k < 16; ++k) {
      const float4 wv = *(const float4*)&wr[k * 4];
      qo[(size_t)(ph * 64 + k * 4 + 0) * HW] = wv.x;
      qo[(size_t)(ph * 64 + k * 4 + 1) * HW] = wv.y;
      qo[(size_t)(ph * 64 + k * 4 + 2) * HW] = wv.z;
      qo[(size_t)(ph * 64 + k * 4 + 3) * HW] = wv.w;
    }
  }
}

extern "C" void kernel_launch(void* const* d_in, const int* in_sizes, int n_in,
                              void* d_out, int out_size, void* d_ws, size_t ws_size,
                              hipStream_t stream) {
  const float* x = (const float*)d_in[0];   // [64,256,32,32]
  const float* w = (const float*)d_in[1];   // [1024,256]
  float* out = (float*)d_out;               // [1 + 16777216 + 65536] f32

  char* ws = (char*)d_ws;
  float*     wn   = (float*)ws;                                // 1 MB
  _Float16*  wh2  = (_Float16*)(ws + 1048576);                 // 512 KB (swizzled)
  double*    rinv = (double*)(ws + 1048576 + 524288);          // 8 KB

  hipMemsetAsync(d_out, 0, sizeof(float), stream);   // zero loss accumulator
  hipLaunchKernelGGL(k_norm_w, dim3(NUM_EMB), dim3(256), 0, stream, w, wn, wh2, rinv);
  hipLaunchKernelGGL(k_fused, dim3(N_ROWS / 64), dim3(256), 0, stream, x, wh2, w, wn, rinv, out);
}